// Round 6
// baseline (552.115 us; speedup 1.0000x reference)
//
#include <hip/hip_runtime.h>
#include <math.h>

#define DDIM 256
#define NSPLIT 4
#define TILES_PER_SPLIT 16   // 16 tiles x 32 codes = 512 codes per split
#define TILE_CODES 32
#define TILE_BYTES 16384     // 32 codes x 256 dims x 2B (panel layout)

typedef __attribute__((ext_vector_type(8))) short short8v;
typedef __attribute__((ext_vector_type(4))) float float4v;
typedef unsigned int u32;
typedef unsigned short u16;

// ---- RNE float -> bf16 ----
__device__ __forceinline__ short f2bf(float x) {
    u32 u = __float_as_uint(x);
    u = u + 0x7fffu + ((u >> 16) & 1u);
    return (short)(u >> 16);
}

// ---- async global->LDS, 16B per lane; lds dst = wave-uniform base + lane*16 ----
__device__ __forceinline__ void gload_lds16(const void* g, void* l) {
    __builtin_amdgcn_global_load_lds(
        (const __attribute__((address_space(1))) u32*)g,
        (__attribute__((address_space(3))) u32*)l, 16, 0, 0);
}

// ---- numpy pairwise-sum simulation (bit-faithful for n=256 contiguous) ----
__device__ __forceinline__ float np_sq_chain(const float* v, int lane) {
    #pragma clang fp contract(off)
    const int half = lane >> 3, j = lane & 7;
    const float* base = v + half * 128 + j;
    float x = base[0];
    float c = x * x;
    #pragma unroll
    for (int m = 1; m < 16; ++m) {
        float y = base[8 * m];
        float s = y * y;
        c = c + s;
    }
    return c;
}

__device__ __forceinline__ float np_combine16(const float* c) {
    #pragma clang fp contract(off)
    float L = ((c[0] + c[1]) + (c[2] + c[3])) + ((c[4] + c[5]) + (c[6] + c[7]));
    float R = ((c[8] + c[9]) + (c[10] + c[11])) + ((c[12] + c[13]) + (c[14] + c[15]));
    return L + R;
}

// ---- top-3 insertion (strict <, preserves first-insertion on ties) ----
__device__ __forceinline__ void ins3(float m, int k,
                                     float& v0, float& v1, float& v2,
                                     int& i0, int& i1, int& i2) {
    if (m < v0)      { v2 = v1; i2 = i1; v1 = v0; i1 = i0; v0 = m; i0 = k; }
    else if (m < v1) { v2 = v1; i2 = i1; v1 = m;  i1 = k; }
    else if (m < v2) { v2 = m;  i2 = k; }
}

// ---------------- kernel 1: zero counts ----------------
__global__ void zero_counts_kernel(int* __restrict__ counts, int K) {
    int i = blockIdx.x * 256 + threadIdx.x;
    if (i < K) counts[i] = 0;
}

// ---------------- kernel 2: numpy-faithful code norms ||e_k||^2 ----------------
__global__ void code_norms_np_kernel(const float* __restrict__ e, float* __restrict__ e2) {
    __shared__ float buf[DDIM];
    __shared__ float ch[16];
    int k = blockIdx.x;
    int t = threadIdx.x;  // 64 threads = 1 wave
    float4 v = *(const float4*)&e[(size_t)k * DDIM + t * 4];
    *(float4*)&buf[t * 4] = v;
    __syncthreads();
    if (t < 16) ch[t] = np_sq_chain(buf, t);
    __syncthreads();
    if (t == 0) e2[k] = np_combine16(ch);
}

// ---------------- kernel 2b: convert e -> bf16 panel layout ----------------
// ebf_p[tile=k/32][d8=0..31][r=k%32][8 shorts]; tile = 16KB contiguous.
__global__ void convert_permute_e_kernel(const float* __restrict__ e, char* __restrict__ ebf_p) {
    int id = blockIdx.x * 256 + threadIdx.x;   // id = k*32 + d8, total K*32
    int k = id >> 5, d8 = id & 31;
    const float* s = &e[(size_t)k * DDIM + d8 * 8];
    float4 f0 = *(const float4*)s;
    float4 f1 = *(const float4*)(s + 4);
    short8v v;
    v[0] = f2bf(f0.x); v[1] = f2bf(f0.y); v[2] = f2bf(f0.z); v[3] = f2bf(f0.w);
    v[4] = f2bf(f1.x); v[5] = f2bf(f1.y); v[6] = f2bf(f1.z); v[7] = f2bf(f1.w);
    *(short8v*)(ebf_p + ((size_t)(k >> 5) << 14) + d8 * 512 + (k & 31) * 16) = v;
}

// ---------------- kernel 3: bf16 MFMA candidate kernel ----------------
// grid = (N/128, 4 splits). Block = 4 waves; wave owns 32 z-rows (64 VGPRs of
// register-resident bf16 B-fragments -> NO spills). Codes double-buffered in
// 32KB static LDS via global_load_lds. Emits per-split top-3 (score+idx).
__global__ __launch_bounds__(256, 3)
void vq_cand_kernel(const float* __restrict__ z, const char* __restrict__ ebf_p,
                    const float* __restrict__ e2, float* __restrict__ cand_v,
                    u16* __restrict__ cand_i) {
    __shared__ char smem[2][TILE_BYTES];
    const int t    = threadIdx.x;
    const int w    = t >> 6;
    const int lane = t & 63;
    const int quad = lane >> 4;
    const int l15  = lane & 15;
    const int s    = blockIdx.y;
    const int row0 = blockIdx.x * 128;
    const int rw0  = row0 + w * 32;

    const char* tile_base = ebf_p + (size_t)s * TILES_PER_SPLIT * TILE_BYTES;

    // prefetch tile 0 into buf0 (before z loads so it overlaps them)
    {
        const char* src = tile_base + w * 4096 + lane * 16;
        char* dst = smem[0] + w * 4096;
        #pragma unroll
        for (int q = 0; q < 4; ++q) gload_lds16(src + q * 1024, dst + q * 1024);
    }

    // ---- persistent z fragments: 32 rows x 256 dims per wave (64 VGPRs) ----
    short8v zf[2][8];
    #pragma unroll
    for (int j = 0; j < 2; ++j) {
        const float* zr = &z[(size_t)(rw0 + j * 16 + l15) * DDIM];
        #pragma unroll
        for (int kk = 0; kk < 8; ++kk) {
            int d0 = kk * 32 + quad * 8;
            float4 f0 = *(const float4*)&zr[d0];
            float4 f1 = *(const float4*)&zr[d0 + 4];
            short8v v;
            v[0] = f2bf(f0.x); v[1] = f2bf(f0.y); v[2] = f2bf(f0.z); v[3] = f2bf(f0.w);
            v[4] = f2bf(f1.x); v[5] = f2bf(f1.y); v[6] = f2bf(f1.z); v[7] = f2bf(f1.w);
            zf[j][kk] = v;
        }
    }

    float v0[2], v1[2], v2[2];
    int   i0[2], i1[2], i2[2];
    #pragma unroll
    for (int j = 0; j < 2; ++j) {
        v0[j] = 3.4e38f; v1[j] = 3.4e38f; v2[j] = 3.4e38f;
        i0[j] = 0x7fff;  i1[j] = 0x7fff;  i2[j] = 0x7fff;
    }

    __syncthreads();   // tile 0 landed (barrier drains vmcnt)

    #pragma unroll 1
    for (int tt = 0; tt < TILES_PER_SPLIT; ++tt) {
        if (tt + 1 < TILES_PER_SPLIT) {
            const char* src = tile_base + (size_t)(tt + 1) * TILE_BYTES + w * 4096 + lane * 16;
            char* dst = smem[(tt + 1) & 1] + w * 4096;
            #pragma unroll
            for (int q = 0; q < 4; ++q) gload_lds16(src + q * 1024, dst + q * 1024);
        }
        const char* es = smem[tt & 1];

        float4v acc[2][2];
        #pragma unroll
        for (int i = 0; i < 2; ++i)
            #pragma unroll
            for (int j = 0; j < 2; ++j) acc[i][j] = (float4v)0.0f;

        #pragma unroll
        for (int kk = 0; kk < 8; ++kk) {
            int c = kk * 4 + quad;  // d8 chunk
            short8v a0 = *(const short8v*)(es + c * 512 + l15 * 16);        // codes 0..15
            short8v a1 = *(const short8v*)(es + c * 512 + (16 + l15) * 16); // codes 16..31
            acc[0][0] = __builtin_amdgcn_mfma_f32_16x16x32_bf16(a0, zf[0][kk], acc[0][0], 0, 0, 0);
            acc[0][1] = __builtin_amdgcn_mfma_f32_16x16x32_bf16(a0, zf[1][kk], acc[0][1], 0, 0, 0);
            acc[1][0] = __builtin_amdgcn_mfma_f32_16x16x32_bf16(a1, zf[0][kk], acc[1][0], 0, 0, 0);
            acc[1][1] = __builtin_amdgcn_mfma_f32_16x16x32_bf16(a1, zf[1][kk], acc[1][1], 0, 0, 0);
        }

        // epilogue: fold tile scores m(k)=e2[k]-2S into per-row top-3
        const int kbase = s * 512 + tt * TILE_CODES;
        #pragma unroll
        for (int i = 0; i < 2; ++i) {
            #pragma unroll
            for (int reg = 0; reg < 4; ++reg) {
                int cl = i * 16 + quad * 4 + reg;
                float ev = e2[kbase + cl];
                int   kc = kbase + cl;
                #pragma unroll
                for (int j = 0; j < 2; ++j) {
                    float m = fmaf(-2.0f, acc[i][j][reg], ev);
                    ins3(m, kc, v0[j], v1[j], v2[j], i0[j], i1[j], i2[j]);
                }
            }
        }
        __syncthreads();  // drains next-tile prefetch; guards buffer reuse
    }

    // ---- cross-quad merge via shuffles: 4 quads x top-3 -> split top-3 ----
    #pragma unroll
    for (int j = 0; j < 2; ++j) {
        float bm0 = 3.4e38f, bm1 = 3.4e38f, bm2 = 3.4e38f;
        int   bk0 = 0x7fff,  bk1 = 0x7fff,  bk2 = 0x7fff;
        #pragma unroll
        for (int q = 0; q < 4; ++q) {
            int src = l15 + q * 16;
            float m0 = __shfl(v0[j], src); int k0 = __shfl(i0[j], src);
            float m1 = __shfl(v1[j], src); int k1 = __shfl(i1[j], src);
            float m2 = __shfl(v2[j], src); int k2 = __shfl(i2[j], src);
            ins3(m0, k0, bm0, bm1, bm2, bk0, bk1, bk2);
            ins3(m1, k1, bm0, bm1, bm2, bk0, bk1, bk2);
            ins3(m2, k2, bm0, bm1, bm2, bk0, bk1, bk2);
        }
        if (quad == 0) {
            size_t base = (size_t)(rw0 + j * 16 + l15) * 12 + s * 3;
            cand_v[base]     = bm0;  cand_i[base]     = (u16)bk0;
            cand_v[base + 1] = bm1;  cand_i[base + 1] = (u16)bk1;
            cand_v[base + 2] = bm2;  cand_i[base + 2] = (u16)bk2;
        }
    }
}

// ---------------- kernel 4: prefilter + np-faithful re-rank + gather + loss ----------------
// One wave per row. Prefilter 12 bf16-scored candidates -> top-6, exact fp64
// dots on 6, numpy-fp32-faithful distance ranking, fused gather + partials.
__global__ void refine_fused_kernel(const float* __restrict__ z, const float* __restrict__ e,
                                    const float* __restrict__ e2np,
                                    const float* __restrict__ cand_v,
                                    const u16* __restrict__ cand_i,
                                    int* __restrict__ counts, float* __restrict__ partials,
                                    float* __restrict__ out_zq, float* __restrict__ out_idx) {
    __shared__ float buf[4][DDIM];
    __shared__ float ch[4][16];
    __shared__ float wsum[4];
    const int w = threadIdx.x >> 6;
    const int t = threadIdx.x & 63;
    const int n = blockIdx.x * 4 + w;

    float4 zv = *(const float4*)&z[(size_t)n * DDIM + t * 4];
    *(float4*)&buf[w][t * 4] = zv;
    __syncthreads();
    if (t < 16) ch[w][t] = np_sq_chain(buf[w], t);
    __syncthreads();

    // ---- prefilter: 12 -> top-6 by bf16 score (uniform across wave) ----
    float bv[6]; int bi[6];
    #pragma unroll
    for (int c = 0; c < 6; ++c) { bv[c] = 3.4e38f; bi[c] = 0x7fffffff; }
    #pragma unroll
    for (int c = 0; c < 12; ++c) {
        float v  = cand_v[(size_t)n * 12 + c];
        int   id = (int)cand_i[(size_t)n * 12 + c];
        #pragma unroll
        for (int x = 0; x < 6; ++x) {
            if (v < bv[x] || (v == bv[x] && id < bi[x])) {
                for (int d = 5; d > x; --d) { bv[d] = bv[d - 1]; bi[d] = bi[d - 1]; }
                bv[x] = v; bi[x] = id;
                break;
            }
        }
    }

    float dotf[6];
    #pragma unroll
    for (int c = 0; c < 6; ++c) {
        int k = bi[c];
        float4 ev = *(const float4*)&e[(size_t)k * DDIM + t * 4];
        double p = (double)zv.x * (double)ev.x + (double)zv.y * (double)ev.y
                 + (double)zv.z * (double)ev.z + (double)zv.w * (double)ev.w;
        #pragma unroll
        for (int o = 32; o > 0; o >>= 1) p += __shfl_down(p, o);
        dotf[c] = (float)p;   // correctly-rounded fp32 of exact dot
    }

    int bk = 0;
    if (t == 0) {
        #pragma clang fp contract(off)
        float sx = np_combine16(ch[w]);
        float bd = 3.4e38f;
        bk = 0x7fffffff;
        #pragma unroll
        for (int c = 0; c < 6; ++c) {
            float twod = 2.0f * dotf[c];
            float t1 = sx - twod;
            float d2v = t1 + e2np[bi[c]];
            d2v = fmaxf(d2v, 0.0f);
            float d = sqrtf(d2v);
            if (d < bd || (d == bd && bi[c] < bk)) { bd = d; bk = bi[c]; }
        }
    }
    int wk = __shfl(bk, 0);

    float4 ev = *(const float4*)&e[(size_t)wk * DDIM + t * 4];
    *(float4*)&out_zq[(size_t)n * DDIM + t * 4] = ev;
    float dx = zv.x - ev.x, dy = zv.y - ev.y, dz = zv.z - ev.z, dw = zv.w - ev.w;
    float sq = dx * dx + dy * dy + dz * dz + dw * dw;
    #pragma unroll
    for (int o = 32; o > 0; o >>= 1) sq += __shfl_down(sq, o);
    if (t == 0) {
        wsum[w] = sq;
        atomicAdd(&counts[wk], 1);
        out_idx[n] = (float)wk;
    }
    __syncthreads();
    if (threadIdx.x == 0)
        partials[blockIdx.x] = wsum[0] + wsum[1] + wsum[2] + wsum[3];
}

// ---------------- kernel 5: finalize loss ----------------
__global__ void finalize_kernel(const int* __restrict__ counts, const float* __restrict__ partials,
                                float* __restrict__ out_loss, int K, int NB,
                                float invN, float invND) {
    int t = threadIdx.x;
    double ent = 0.0, sq = 0.0;
    for (int k = t; k < K; k += 256) {
        float p = (float)counts[k] * invN;
        ent += (double)(p * logf(p + 1e-10f));
    }
    for (int i = t; i < NB; i += 256) sq += (double)partials[i];
    #pragma unroll
    for (int o = 32; o > 0; o >>= 1) {
        ent += __shfl_down(ent, o);
        sq  += __shfl_down(sq, o);
    }
    __shared__ double e4[4], s4[4];
    if ((t & 63) == 0) { e4[t >> 6] = ent; s4[t >> 6] = sq; }
    __syncthreads();
    if (t == 0) {
        double esum = e4[0] + e4[1] + e4[2] + e4[3];
        double ssum = s4[0] + s4[1] + s4[2] + s4[3];
        float perp = expf((float)(-esum));
        float mean = (float)ssum * invND;
        out_loss[0] = 1.25f * mean - 0.01f * perp;
    }
}

extern "C" void kernel_launch(void* const* d_in, const int* in_sizes, int n_in,
                              void* d_out, int out_size, void* d_ws, size_t ws_size,
                              hipStream_t stream) {
    const float* z = (const float*)d_in[0];
    const float* e = (const float*)d_in[1];
    const int N = in_sizes[0] / DDIM;   // 32768
    const int K = in_sizes[1] / DDIM;   // 2048

    float* out      = (float*)d_out;
    float* out_zq   = out;
    float* out_loss = out + (size_t)N * DDIM;
    float* out_idx  = out_loss + 1;

    // ws layout (bytes):
    //   counts[K]            @ 0        (8 KB)
    //   e2np[K]              @ 8192     (8 KB)
    //   partials[N/4]        @ 16384    (32 KB)
    //   cand_v[N*12] f32     @ 49152    (1.5 MB)
    //   cand_i[N*12] u16     @ 1622016  (768 KB)
    //   ebf_p (1 MB panels)  @ 2408448  -> total ~3.46 MB
    int*   counts   = (int*)d_ws;
    float* e2np     = (float*)((char*)d_ws + 8192);
    float* partials = (float*)((char*)d_ws + 16384);
    float* cand_v   = (float*)((char*)d_ws + 49152);
    u16*   cand_i   = (u16*)((char*)d_ws + 1622016);
    char*  ebf_p    = (char*)d_ws + 2408448;

    zero_counts_kernel<<<(K + 255) / 256, 256, 0, stream>>>(counts, K);
    code_norms_np_kernel<<<K, 64, 0, stream>>>(e, e2np);
    convert_permute_e_kernel<<<K * 32 / 256, 256, 0, stream>>>(e, ebf_p);
    vq_cand_kernel<<<dim3(N / 128, NSPLIT), 256, 0, stream>>>(z, ebf_p, e2np, cand_v, cand_i);
    refine_fused_kernel<<<N / 4, 256, 0, stream>>>(z, e, e2np, cand_v, cand_i,
                                                   counts, partials, out_zq, out_idx);
    finalize_kernel<<<1, 256, 0, stream>>>(counts, partials, out_loss, K, N / 4,
                                           1.0f / (float)N, 1.0f / (float)(N * DDIM));
}

// Round 7
// 459.791 us; speedup vs baseline: 1.2008x; 1.2008x over previous
//
#include <hip/hip_runtime.h>
#include <math.h>

#define DDIM 256
#define NSPLIT 4
#define TILES_PER_SPLIT 16   // 16 tiles x 32 codes = 512 codes per split
#define TILE_CODES 32
#define TILE_BYTES 16384     // 32 codes x 256 dims x 2B (panel layout)

typedef __attribute__((ext_vector_type(8))) short short8v;
typedef __attribute__((ext_vector_type(4))) float float4v;
typedef unsigned int u32;
typedef unsigned short u16;

// ---- RNE float -> bf16 ----
__device__ __forceinline__ short f2bf(float x) {
    u32 u = __float_as_uint(x);
    u = u + 0x7fffu + ((u >> 16) & 1u);
    return (short)(u >> 16);
}

// ---- async global->LDS, 16B per lane; lds dst = wave-uniform base + lane*16 ----
__device__ __forceinline__ void gload_lds16(const void* g, void* l) {
    __builtin_amdgcn_global_load_lds(
        (const __attribute__((address_space(1))) u32*)g,
        (__attribute__((address_space(3))) u32*)l, 16, 0, 0);
}

// ---- numpy pairwise-sum simulation (bit-faithful for n=256 contiguous) ----
__device__ __forceinline__ float np_sq_chain(const float* v, int lane) {
    #pragma clang fp contract(off)
    const int half = lane >> 3, j = lane & 7;
    const float* base = v + half * 128 + j;
    float x = base[0];
    float c = x * x;
    #pragma unroll
    for (int m = 1; m < 16; ++m) {
        float y = base[8 * m];
        float s = y * y;
        c = c + s;
    }
    return c;
}

__device__ __forceinline__ float np_combine16(const float* c) {
    #pragma clang fp contract(off)
    float L = ((c[0] + c[1]) + (c[2] + c[3])) + ((c[4] + c[5]) + (c[6] + c[7]));
    float R = ((c[8] + c[9]) + (c[10] + c[11])) + ((c[12] + c[13]) + (c[14] + c[15]));
    return L + R;
}

// ---- top-3 insertion (strict <, preserves first-insertion on ties) ----
__device__ __forceinline__ void ins3(float m, int k,
                                     float& v0, float& v1, float& v2,
                                     int& i0, int& i1, int& i2) {
    if (m < v0)      { v2 = v1; i2 = i1; v1 = v0; i1 = i0; v0 = m; i0 = k; }
    else if (m < v1) { v2 = v1; i2 = i1; v1 = m;  i1 = k; }
    else if (m < v2) { v2 = m;  i2 = k; }
}

// ---------------- kernel 1: zero counts ----------------
__global__ void zero_counts_kernel(int* __restrict__ counts, int K) {
    int i = blockIdx.x * 256 + threadIdx.x;
    if (i < K) counts[i] = 0;
}

// ---------------- kernel 2: numpy-faithful code norms ||e_k||^2 ----------------
__global__ void code_norms_np_kernel(const float* __restrict__ e, float* __restrict__ e2) {
    __shared__ float buf[DDIM];
    __shared__ float ch[16];
    int k = blockIdx.x;
    int t = threadIdx.x;  // 64 threads = 1 wave
    float4 v = *(const float4*)&e[(size_t)k * DDIM + t * 4];
    *(float4*)&buf[t * 4] = v;
    __syncthreads();
    if (t < 16) ch[t] = np_sq_chain(buf, t);
    __syncthreads();
    if (t == 0) e2[k] = np_combine16(ch);
}

// ---------------- kernel 2b: convert e -> bf16 panel layout ----------------
// ebf_p[tile=k/32][d8=0..31][r=k%32][8 shorts]; tile = 16KB contiguous.
__global__ void convert_permute_e_kernel(const float* __restrict__ e, char* __restrict__ ebf_p) {
    int id = blockIdx.x * 256 + threadIdx.x;   // id = k*32 + d8, total K*32
    int k = id >> 5, d8 = id & 31;
    const float* s = &e[(size_t)k * DDIM + d8 * 8];
    float4 f0 = *(const float4*)s;
    float4 f1 = *(const float4*)(s + 4);
    short8v v;
    v[0] = f2bf(f0.x); v[1] = f2bf(f0.y); v[2] = f2bf(f0.z); v[3] = f2bf(f0.w);
    v[4] = f2bf(f1.x); v[5] = f2bf(f1.y); v[6] = f2bf(f1.z); v[7] = f2bf(f1.w);
    *(short8v*)(ebf_p + ((size_t)(k >> 5) << 14) + d8 * 512 + (k & 31) * 16) = v;
}

// ---------------- kernel 3: bf16 MFMA candidate kernel ----------------
// grid = (N/64, 4 splits). Block = 4 waves; wave owns 16 z-rows -> zf[8] is
// only 32 VGPRs (live set ~80 regs: no spill possible). Codes double-buffered
// in 32KB static LDS via global_load_lds. Emits per-split top-3 (score+idx).
__global__ __launch_bounds__(256)
void vq_cand_kernel(const float* __restrict__ z, const char* __restrict__ ebf_p,
                    const float* __restrict__ e2, float* __restrict__ cand_v,
                    u16* __restrict__ cand_i) {
    __shared__ char smem[2][TILE_BYTES];
    const int t    = threadIdx.x;
    const int w    = t >> 6;
    const int lane = t & 63;
    const int quad = lane >> 4;
    const int l15  = lane & 15;
    const int s    = blockIdx.y;
    const int row0 = blockIdx.x * 64;
    const int rw0  = row0 + w * 16;

    const char* tile_base = ebf_p + (size_t)s * TILES_PER_SPLIT * TILE_BYTES;

    // prefetch tile 0 into buf0 (before z loads so it overlaps them)
    {
        const char* src = tile_base + w * 4096 + lane * 16;
        char* dst = smem[0] + w * 4096;
        #pragma unroll
        for (int q = 0; q < 4; ++q) gload_lds16(src + q * 1024, dst + q * 1024);
    }

    // ---- persistent z fragments: 16 rows x 256 dims per wave (32 VGPRs) ----
    short8v zf[8];
    {
        const float* zr = &z[(size_t)(rw0 + l15) * DDIM];
        #pragma unroll
        for (int kk = 0; kk < 8; ++kk) {
            int d0 = kk * 32 + quad * 8;
            float4 f0 = *(const float4*)&zr[d0];
            float4 f1 = *(const float4*)&zr[d0 + 4];
            short8v v;
            v[0] = f2bf(f0.x); v[1] = f2bf(f0.y); v[2] = f2bf(f0.z); v[3] = f2bf(f0.w);
            v[4] = f2bf(f1.x); v[5] = f2bf(f1.y); v[6] = f2bf(f1.z); v[7] = f2bf(f1.w);
            zf[kk] = v;
        }
    }

    float v0 = 3.4e38f, v1 = 3.4e38f, v2 = 3.4e38f;
    int   i0 = 0x7fff,  i1 = 0x7fff,  i2 = 0x7fff;

    __syncthreads();   // tile 0 landed (barrier drains vmcnt)

    #pragma unroll 1
    for (int tt = 0; tt < TILES_PER_SPLIT; ++tt) {
        if (tt + 1 < TILES_PER_SPLIT) {
            const char* src = tile_base + (size_t)(tt + 1) * TILE_BYTES + w * 4096 + lane * 16;
            char* dst = smem[(tt + 1) & 1] + w * 4096;
            #pragma unroll
            for (int q = 0; q < 4; ++q) gload_lds16(src + q * 1024, dst + q * 1024);
        }
        const char* es = smem[tt & 1];

        float4v acc0 = (float4v)0.0f, acc1 = (float4v)0.0f;

        #pragma unroll
        for (int kk = 0; kk < 8; ++kk) {
            int c = kk * 4 + quad;  // d8 chunk
            short8v a0 = *(const short8v*)(es + c * 512 + l15 * 16);        // codes 0..15
            short8v a1 = *(const short8v*)(es + c * 512 + (16 + l15) * 16); // codes 16..31
            acc0 = __builtin_amdgcn_mfma_f32_16x16x32_bf16(a0, zf[kk], acc0, 0, 0, 0);
            acc1 = __builtin_amdgcn_mfma_f32_16x16x32_bf16(a1, zf[kk], acc1, 0, 0, 0);
        }

        // epilogue: fold tile scores m(k)=e2[k]-2S into per-row top-3
        const int kbase = s * 512 + tt * TILE_CODES;
        #pragma unroll
        for (int reg = 0; reg < 4; ++reg) {
            int cl0 = quad * 4 + reg;
            float m0 = fmaf(-2.0f, acc0[reg], e2[kbase + cl0]);
            ins3(m0, kbase + cl0, v0, v1, v2, i0, i1, i2);
            int cl1 = 16 + quad * 4 + reg;
            float m1 = fmaf(-2.0f, acc1[reg], e2[kbase + cl1]);
            ins3(m1, kbase + cl1, v0, v1, v2, i0, i1, i2);
        }
        __syncthreads();  // drains next-tile prefetch; guards buffer reuse
    }

    // ---- cross-quad merge via shuffles: 4 quads x top-3 -> split top-3 ----
    {
        float bm0 = 3.4e38f, bm1 = 3.4e38f, bm2 = 3.4e38f;
        int   bk0 = 0x7fff,  bk1 = 0x7fff,  bk2 = 0x7fff;
        #pragma unroll
        for (int q = 0; q < 4; ++q) {
            int src = l15 + q * 16;
            float m0 = __shfl(v0, src); int k0 = __shfl(i0, src);
            float m1 = __shfl(v1, src); int k1 = __shfl(i1, src);
            float m2 = __shfl(v2, src); int k2 = __shfl(i2, src);
            ins3(m0, k0, bm0, bm1, bm2, bk0, bk1, bk2);
            ins3(m1, k1, bm0, bm1, bm2, bk0, bk1, bk2);
            ins3(m2, k2, bm0, bm1, bm2, bk0, bk1, bk2);
        }
        if (quad == 0) {
            size_t base = (size_t)(rw0 + l15) * 12 + s * 3;
            cand_v[base]     = bm0;  cand_i[base]     = (u16)bk0;
            cand_v[base + 1] = bm1;  cand_i[base + 1] = (u16)bk1;
            cand_v[base + 2] = bm2;  cand_i[base + 2] = (u16)bk2;
        }
    }
}

// ---------------- kernel 4: prefilter + np-faithful re-rank + gather + loss ----------------
// One wave per row. Prefilter 12 bf16-scored candidates -> top-6, exact fp64
// dots on 6, numpy-fp32-faithful distance ranking, fused gather + partials.
__global__ void refine_fused_kernel(const float* __restrict__ z, const float* __restrict__ e,
                                    const float* __restrict__ e2np,
                                    const float* __restrict__ cand_v,
                                    const u16* __restrict__ cand_i,
                                    int* __restrict__ counts, float* __restrict__ partials,
                                    float* __restrict__ out_zq, float* __restrict__ out_idx) {
    __shared__ float buf[4][DDIM];
    __shared__ float ch[4][16];
    __shared__ float wsum[4];
    const int w = threadIdx.x >> 6;
    const int t = threadIdx.x & 63;
    const int n = blockIdx.x * 4 + w;

    float4 zv = *(const float4*)&z[(size_t)n * DDIM + t * 4];
    *(float4*)&buf[w][t * 4] = zv;
    __syncthreads();
    if (t < 16) ch[w][t] = np_sq_chain(buf[w], t);
    __syncthreads();

    // ---- prefilter: 12 -> top-6 by bf16 score (uniform across wave) ----
    float bv[6]; int bi[6];
    #pragma unroll
    for (int c = 0; c < 6; ++c) { bv[c] = 3.4e38f; bi[c] = 0x7fffffff; }
    #pragma unroll
    for (int c = 0; c < 12; ++c) {
        float v  = cand_v[(size_t)n * 12 + c];
        int   id = (int)cand_i[(size_t)n * 12 + c];
        #pragma unroll
        for (int x = 0; x < 6; ++x) {
            if (v < bv[x] || (v == bv[x] && id < bi[x])) {
                for (int d = 5; d > x; --d) { bv[d] = bv[d - 1]; bi[d] = bi[d - 1]; }
                bv[x] = v; bi[x] = id;
                break;
            }
        }
    }

    float dotf[6];
    #pragma unroll
    for (int c = 0; c < 6; ++c) {
        int k = bi[c];
        float4 ev = *(const float4*)&e[(size_t)k * DDIM + t * 4];
        double p = (double)zv.x * (double)ev.x + (double)zv.y * (double)ev.y
                 + (double)zv.z * (double)ev.z + (double)zv.w * (double)ev.w;
        #pragma unroll
        for (int o = 32; o > 0; o >>= 1) p += __shfl_down(p, o);
        dotf[c] = (float)p;   // correctly-rounded fp32 of exact dot
    }

    int bk = 0;
    if (t == 0) {
        #pragma clang fp contract(off)
        float sx = np_combine16(ch[w]);
        float bd = 3.4e38f;
        bk = 0x7fffffff;
        #pragma unroll
        for (int c = 0; c < 6; ++c) {
            float twod = 2.0f * dotf[c];
            float t1 = sx - twod;
            float d2v = t1 + e2np[bi[c]];
            d2v = fmaxf(d2v, 0.0f);
            float d = sqrtf(d2v);
            if (d < bd || (d == bd && bi[c] < bk)) { bd = d; bk = bi[c]; }
        }
    }
    int wk = __shfl(bk, 0);

    float4 ev = *(const float4*)&e[(size_t)wk * DDIM + t * 4];
    *(float4*)&out_zq[(size_t)n * DDIM + t * 4] = ev;
    float dx = zv.x - ev.x, dy = zv.y - ev.y, dz = zv.z - ev.z, dw = zv.w - ev.w;
    float sq = dx * dx + dy * dy + dz * dz + dw * dw;
    #pragma unroll
    for (int o = 32; o > 0; o >>= 1) sq += __shfl_down(sq, o);
    if (t == 0) {
        wsum[w] = sq;
        atomicAdd(&counts[wk], 1);
        out_idx[n] = (float)wk;
    }
    __syncthreads();
    if (threadIdx.x == 0)
        partials[blockIdx.x] = wsum[0] + wsum[1] + wsum[2] + wsum[3];
}

// ---------------- kernel 5: finalize loss ----------------
__global__ void finalize_kernel(const int* __restrict__ counts, const float* __restrict__ partials,
                                float* __restrict__ out_loss, int K, int NB,
                                float invN, float invND) {
    int t = threadIdx.x;
    double ent = 0.0, sq = 0.0;
    for (int k = t; k < K; k += 256) {
        float p = (float)counts[k] * invN;
        ent += (double)(p * logf(p + 1e-10f));
    }
    for (int i = t; i < NB; i += 256) sq += (double)partials[i];
    #pragma unroll
    for (int o = 32; o > 0; o >>= 1) {
        ent += __shfl_down(ent, o);
        sq  += __shfl_down(sq, o);
    }
    __shared__ double e4[4], s4[4];
    if ((t & 63) == 0) { e4[t >> 6] = ent; s4[t >> 6] = sq; }
    __syncthreads();
    if (t == 0) {
        double esum = e4[0] + e4[1] + e4[2] + e4[3];
        double ssum = s4[0] + s4[1] + s4[2] + s4[3];
        float perp = expf((float)(-esum));
        float mean = (float)ssum * invND;
        out_loss[0] = 1.25f * mean - 0.01f * perp;
    }
}

extern "C" void kernel_launch(void* const* d_in, const int* in_sizes, int n_in,
                              void* d_out, int out_size, void* d_ws, size_t ws_size,
                              hipStream_t stream) {
    const float* z = (const float*)d_in[0];
    const float* e = (const float*)d_in[1];
    const int N = in_sizes[0] / DDIM;   // 32768
    const int K = in_sizes[1] / DDIM;   // 2048

    float* out      = (float*)d_out;
    float* out_zq   = out;
    float* out_loss = out + (size_t)N * DDIM;
    float* out_idx  = out_loss + 1;

    // ws layout (bytes):
    //   counts[K]            @ 0        (8 KB)
    //   e2np[K]              @ 8192     (8 KB)
    //   partials[N/4]        @ 16384    (32 KB)
    //   cand_v[N*12] f32     @ 49152    (1.5 MB)
    //   cand_i[N*12] u16     @ 1622016  (768 KB)
    //   ebf_p (1 MB panels)  @ 2408448  -> total ~3.46 MB
    int*   counts   = (int*)d_ws;
    float* e2np     = (float*)((char*)d_ws + 8192);
    float* partials = (float*)((char*)d_ws + 16384);
    float* cand_v   = (float*)((char*)d_ws + 49152);
    u16*   cand_i   = (u16*)((char*)d_ws + 1622016);
    char*  ebf_p    = (char*)d_ws + 2408448;

    zero_counts_kernel<<<(K + 255) / 256, 256, 0, stream>>>(counts, K);
    code_norms_np_kernel<<<K, 64, 0, stream>>>(e, e2np);
    convert_permute_e_kernel<<<K * 32 / 256, 256, 0, stream>>>(e, ebf_p);
    vq_cand_kernel<<<dim3(N / 64, NSPLIT), 256, 0, stream>>>(z, ebf_p, e2np, cand_v, cand_i);
    refine_fused_kernel<<<N / 4, 256, 0, stream>>>(z, e, e2np, cand_v, cand_i,
                                                   counts, partials, out_zq, out_idx);
    finalize_kernel<<<1, 256, 0, stream>>>(counts, partials, out_loss, K, N / 4,
                                           1.0f / (float)N, 1.0f / (float)(N * DDIM));
}

// Round 8
// 455.334 us; speedup vs baseline: 1.2126x; 1.0098x over previous
//
#include <hip/hip_runtime.h>
#include <math.h>

#define DDIM 256
#define NSPLIT 4
#define TILES_PER_SPLIT 16   // 16 tiles x 32 codes = 512 codes per split
#define TILE_CODES 32
#define TILE_BYTES 16384     // 32 codes x 256 dims x 2B (panel layout)

typedef __attribute__((ext_vector_type(8))) short short8v;
typedef __attribute__((ext_vector_type(4))) float float4v;
typedef unsigned int u32;
typedef unsigned short u16;

// ---- RNE float -> bf16 ----
__device__ __forceinline__ short f2bf(float x) {
    u32 u = __float_as_uint(x);
    u = u + 0x7fffu + ((u >> 16) & 1u);
    return (short)(u >> 16);
}

// ---- async global->LDS, 16B per lane; lds dst = wave-uniform base + lane*16 ----
__device__ __forceinline__ void gload_lds16(const void* g, void* l) {
    __builtin_amdgcn_global_load_lds(
        (const __attribute__((address_space(1))) u32*)g,
        (__attribute__((address_space(3))) u32*)l, 16, 0, 0);
}

// ---- numpy pairwise-sum simulation (bit-faithful for n=256 contiguous) ----
__device__ __forceinline__ float np_sq_chain(const float* v, int lane) {
    #pragma clang fp contract(off)
    const int half = lane >> 3, j = lane & 7;
    const float* base = v + half * 128 + j;
    float x = base[0];
    float c = x * x;
    #pragma unroll
    for (int m = 1; m < 16; ++m) {
        float y = base[8 * m];
        float s = y * y;
        c = c + s;
    }
    return c;
}

__device__ __forceinline__ float np_combine16(const float* c) {
    #pragma clang fp contract(off)
    float L = ((c[0] + c[1]) + (c[2] + c[3])) + ((c[4] + c[5]) + (c[6] + c[7]));
    float R = ((c[8] + c[9]) + (c[10] + c[11])) + ((c[12] + c[13]) + (c[14] + c[15]));
    return L + R;
}

// ---- top-3 insertion (strict <, preserves first-insertion on ties) ----
__device__ __forceinline__ void ins3(float m, int k,
                                     float& v0, float& v1, float& v2,
                                     int& i0, int& i1, int& i2) {
    if (m < v0)      { v2 = v1; i2 = i1; v1 = v0; i1 = i0; v0 = m; i0 = k; }
    else if (m < v1) { v2 = v1; i2 = i1; v1 = m;  i1 = k; }
    else if (m < v2) { v2 = m;  i2 = k; }
}

// ---------------- kernel 1: zero counts ----------------
__global__ void zero_counts_kernel(int* __restrict__ counts, int K) {
    int i = blockIdx.x * 256 + threadIdx.x;
    if (i < K) counts[i] = 0;
}

// ---------------- kernel 2: numpy-faithful code norms ||e_k||^2 ----------------
__global__ void code_norms_np_kernel(const float* __restrict__ e, float* __restrict__ e2) {
    __shared__ float buf[DDIM];
    __shared__ float ch[16];
    int k = blockIdx.x;
    int t = threadIdx.x;  // 64 threads = 1 wave
    float4 v = *(const float4*)&e[(size_t)k * DDIM + t * 4];
    *(float4*)&buf[t * 4] = v;
    __syncthreads();
    if (t < 16) ch[t] = np_sq_chain(buf, t);
    __syncthreads();
    if (t == 0) e2[k] = np_combine16(ch);
}

// ---------------- kernel 2b: convert e -> bf16 panel layout ----------------
// ebf_p[tile=k/32][d8=0..31][r=k%32][8 shorts]; tile = 16KB contiguous.
__global__ void convert_permute_e_kernel(const float* __restrict__ e, char* __restrict__ ebf_p) {
    int id = blockIdx.x * 256 + threadIdx.x;   // id = k*32 + d8, total K*32
    int k = id >> 5, d8 = id & 31;
    const float* s = &e[(size_t)k * DDIM + d8 * 8];
    float4 f0 = *(const float4*)s;
    float4 f1 = *(const float4*)(s + 4);
    short8v v;
    v[0] = f2bf(f0.x); v[1] = f2bf(f0.y); v[2] = f2bf(f0.z); v[3] = f2bf(f0.w);
    v[4] = f2bf(f1.x); v[5] = f2bf(f1.y); v[6] = f2bf(f1.z); v[7] = f2bf(f1.w);
    *(short8v*)(ebf_p + ((size_t)(k >> 5) << 14) + d8 * 512 + (k & 31) * 16) = v;
}

// ---------------- kernel 3: bf16 MFMA candidate kernel ----------------
// grid = (N/64, 4 splits). Block = 4 waves; wave owns 16 z-rows (zf[8] = 32
// VGPRs). waves_per_eu(4,4) pins the register budget at 128 so the backend's
// occupancy heuristic cannot spill the persistent z-fragments (R5-R7: it
// targeted 8 waves/EU and spilled zf to scratch -> 40-138 MB WRITE_SIZE).
__global__ __attribute__((amdgpu_flat_work_group_size(256, 256)))
__attribute__((amdgpu_waves_per_eu(4, 4)))
void vq_cand_kernel(const float* __restrict__ z, const char* __restrict__ ebf_p,
                    const float* __restrict__ e2, float* __restrict__ cand_v,
                    u16* __restrict__ cand_i) {
    __shared__ char smem[2][TILE_BYTES];
    const int t    = threadIdx.x;
    const int w    = t >> 6;
    const int lane = t & 63;
    const int quad = lane >> 4;
    const int l15  = lane & 15;
    const int s    = blockIdx.y;
    const int row0 = blockIdx.x * 64;
    const int rw0  = row0 + w * 16;

    const char* tile_base = ebf_p + (size_t)s * TILES_PER_SPLIT * TILE_BYTES;

    // prefetch tile 0 into buf0 (before z loads so it overlaps them)
    {
        const char* src = tile_base + w * 4096 + lane * 16;
        char* dst = smem[0] + w * 4096;
        #pragma unroll
        for (int q = 0; q < 4; ++q) gload_lds16(src + q * 1024, dst + q * 1024);
    }

    // ---- persistent z fragments: 16 rows x 256 dims per wave (32 VGPRs) ----
    short8v zf[8];
    {
        const float* zr = &z[(size_t)(rw0 + l15) * DDIM];
        #pragma unroll
        for (int kk = 0; kk < 8; ++kk) {
            int d0 = kk * 32 + quad * 8;
            float4 f0 = *(const float4*)&zr[d0];
            float4 f1 = *(const float4*)&zr[d0 + 4];
            short8v v;
            v[0] = f2bf(f0.x); v[1] = f2bf(f0.y); v[2] = f2bf(f0.z); v[3] = f2bf(f0.w);
            v[4] = f2bf(f1.x); v[5] = f2bf(f1.y); v[6] = f2bf(f1.z); v[7] = f2bf(f1.w);
            zf[kk] = v;
        }
    }

    float v0 = 3.4e38f, v1 = 3.4e38f, v2 = 3.4e38f;
    int   i0 = 0x7fff,  i1 = 0x7fff,  i2 = 0x7fff;

    __syncthreads();   // tile 0 landed (barrier drains vmcnt)

    #pragma unroll 1
    for (int tt = 0; tt < TILES_PER_SPLIT; ++tt) {
        if (tt + 1 < TILES_PER_SPLIT) {
            const char* src = tile_base + (size_t)(tt + 1) * TILE_BYTES + w * 4096 + lane * 16;
            char* dst = smem[(tt + 1) & 1] + w * 4096;
            #pragma unroll
            for (int q = 0; q < 4; ++q) gload_lds16(src + q * 1024, dst + q * 1024);
        }
        const char* es = smem[tt & 1];

        float4v acc0 = (float4v)0.0f, acc1 = (float4v)0.0f;

        #pragma unroll
        for (int kk = 0; kk < 8; ++kk) {
            int c = kk * 4 + quad;  // d8 chunk
            short8v a0 = *(const short8v*)(es + c * 512 + l15 * 16);        // codes 0..15
            short8v a1 = *(const short8v*)(es + c * 512 + (16 + l15) * 16); // codes 16..31
            acc0 = __builtin_amdgcn_mfma_f32_16x16x32_bf16(a0, zf[kk], acc0, 0, 0, 0);
            acc1 = __builtin_amdgcn_mfma_f32_16x16x32_bf16(a1, zf[kk], acc1, 0, 0, 0);
        }

        // epilogue: fold tile scores m(k)=e2[k]-2S into per-row top-3
        const int kbase = s * 512 + tt * TILE_CODES;
        #pragma unroll
        for (int reg = 0; reg < 4; ++reg) {
            int cl0 = quad * 4 + reg;
            float m0 = fmaf(-2.0f, acc0[reg], e2[kbase + cl0]);
            ins3(m0, kbase + cl0, v0, v1, v2, i0, i1, i2);
            int cl1 = 16 + quad * 4 + reg;
            float m1 = fmaf(-2.0f, acc1[reg], e2[kbase + cl1]);
            ins3(m1, kbase + cl1, v0, v1, v2, i0, i1, i2);
        }
        __syncthreads();  // drains next-tile prefetch; guards buffer reuse
    }

    // ---- cross-quad merge via shuffles: 4 quads x top-3 -> split top-3 ----
    {
        float bm0 = 3.4e38f, bm1 = 3.4e38f, bm2 = 3.4e38f;
        int   bk0 = 0x7fff,  bk1 = 0x7fff,  bk2 = 0x7fff;
        #pragma unroll
        for (int q = 0; q < 4; ++q) {
            int src = l15 + q * 16;
            float m0 = __shfl(v0, src); int k0 = __shfl(i0, src);
            float m1 = __shfl(v1, src); int k1 = __shfl(i1, src);
            float m2 = __shfl(v2, src); int k2 = __shfl(i2, src);
            ins3(m0, k0, bm0, bm1, bm2, bk0, bk1, bk2);
            ins3(m1, k1, bm0, bm1, bm2, bk0, bk1, bk2);
            ins3(m2, k2, bm0, bm1, bm2, bk0, bk1, bk2);
        }
        if (quad == 0) {
            size_t base = (size_t)(rw0 + l15) * 12 + s * 3;
            cand_v[base]     = bm0;  cand_i[base]     = (u16)bk0;
            cand_v[base + 1] = bm1;  cand_i[base + 1] = (u16)bk1;
            cand_v[base + 2] = bm2;  cand_i[base + 2] = (u16)bk2;
        }
    }
}

// ---------------- kernel 4: prefilter + np-faithful re-rank + gather + loss ----------------
// One wave per row. Prefilter 12 bf16-scored candidates -> top-6, exact fp64
// dots on 6, numpy-fp32-faithful distance ranking, fused gather + partials.
__global__ void refine_fused_kernel(const float* __restrict__ z, const float* __restrict__ e,
                                    const float* __restrict__ e2np,
                                    const float* __restrict__ cand_v,
                                    const u16* __restrict__ cand_i,
                                    int* __restrict__ counts, float* __restrict__ partials,
                                    float* __restrict__ out_zq, float* __restrict__ out_idx) {
    __shared__ float buf[4][DDIM];
    __shared__ float ch[4][16];
    __shared__ float wsum[4];
    const int w = threadIdx.x >> 6;
    const int t = threadIdx.x & 63;
    const int n = blockIdx.x * 4 + w;

    float4 zv = *(const float4*)&z[(size_t)n * DDIM + t * 4];
    *(float4*)&buf[w][t * 4] = zv;
    __syncthreads();
    if (t < 16) ch[w][t] = np_sq_chain(buf[w], t);
    __syncthreads();

    // ---- prefilter: 12 -> top-6 by bf16 score (uniform across wave) ----
    float bv[6]; int bi[6];
    #pragma unroll
    for (int c = 0; c < 6; ++c) { bv[c] = 3.4e38f; bi[c] = 0x7fffffff; }
    #pragma unroll
    for (int c = 0; c < 12; ++c) {
        float v  = cand_v[(size_t)n * 12 + c];
        int   id = (int)cand_i[(size_t)n * 12 + c];
        #pragma unroll
        for (int x = 0; x < 6; ++x) {
            if (v < bv[x] || (v == bv[x] && id < bi[x])) {
                for (int d = 5; d > x; --d) { bv[d] = bv[d - 1]; bi[d] = bi[d - 1]; }
                bv[x] = v; bi[x] = id;
                break;
            }
        }
    }

    float dotf[6];
    #pragma unroll
    for (int c = 0; c < 6; ++c) {
        int k = bi[c];
        float4 ev = *(const float4*)&e[(size_t)k * DDIM + t * 4];
        double p = (double)zv.x * (double)ev.x + (double)zv.y * (double)ev.y
                 + (double)zv.z * (double)ev.z + (double)zv.w * (double)ev.w;
        #pragma unroll
        for (int o = 32; o > 0; o >>= 1) p += __shfl_down(p, o);
        dotf[c] = (float)p;   // correctly-rounded fp32 of exact dot
    }

    int bk = 0;
    if (t == 0) {
        #pragma clang fp contract(off)
        float sx = np_combine16(ch[w]);
        float bd = 3.4e38f;
        bk = 0x7fffffff;
        #pragma unroll
        for (int c = 0; c < 6; ++c) {
            float twod = 2.0f * dotf[c];
            float t1 = sx - twod;
            float d2v = t1 + e2np[bi[c]];
            d2v = fmaxf(d2v, 0.0f);
            float d = sqrtf(d2v);
            if (d < bd || (d == bd && bi[c] < bk)) { bd = d; bk = bi[c]; }
        }
    }
    int wk = __shfl(bk, 0);

    float4 ev = *(const float4*)&e[(size_t)wk * DDIM + t * 4];
    *(float4*)&out_zq[(size_t)n * DDIM + t * 4] = ev;
    float dx = zv.x - ev.x, dy = zv.y - ev.y, dz = zv.z - ev.z, dw = zv.w - ev.w;
    float sq = dx * dx + dy * dy + dz * dz + dw * dw;
    #pragma unroll
    for (int o = 32; o > 0; o >>= 1) sq += __shfl_down(sq, o);
    if (t == 0) {
        wsum[w] = sq;
        atomicAdd(&counts[wk], 1);
        out_idx[n] = (float)wk;
    }
    __syncthreads();
    if (threadIdx.x == 0)
        partials[blockIdx.x] = wsum[0] + wsum[1] + wsum[2] + wsum[3];
}

// ---------------- kernel 5: finalize loss ----------------
__global__ void finalize_kernel(const int* __restrict__ counts, const float* __restrict__ partials,
                                float* __restrict__ out_loss, int K, int NB,
                                float invN, float invND) {
    int t = threadIdx.x;
    double ent = 0.0, sq = 0.0;
    for (int k = t; k < K; k += 256) {
        float p = (float)counts[k] * invN;
        ent += (double)(p * logf(p + 1e-10f));
    }
    for (int i = t; i < NB; i += 256) sq += (double)partials[i];
    #pragma unroll
    for (int o = 32; o > 0; o >>= 1) {
        ent += __shfl_down(ent, o);
        sq  += __shfl_down(sq, o);
    }
    __shared__ double e4[4], s4[4];
    if ((t & 63) == 0) { e4[t >> 6] = ent; s4[t >> 6] = sq; }
    __syncthreads();
    if (t == 0) {
        double esum = e4[0] + e4[1] + e4[2] + e4[3];
        double ssum = s4[0] + s4[1] + s4[2] + s4[3];
        float perp = expf((float)(-esum));
        float mean = (float)ssum * invND;
        out_loss[0] = 1.25f * mean - 0.01f * perp;
    }
}

extern "C" void kernel_launch(void* const* d_in, const int* in_sizes, int n_in,
                              void* d_out, int out_size, void* d_ws, size_t ws_size,
                              hipStream_t stream) {
    const float* z = (const float*)d_in[0];
    const float* e = (const float*)d_in[1];
    const int N = in_sizes[0] / DDIM;   // 32768
    const int K = in_sizes[1] / DDIM;   // 2048

    float* out      = (float*)d_out;
    float* out_zq   = out;
    float* out_loss = out + (size_t)N * DDIM;
    float* out_idx  = out_loss + 1;

    // ws layout (bytes):
    //   counts[K]            @ 0        (8 KB)
    //   e2np[K]              @ 8192     (8 KB)
    //   partials[N/4]        @ 16384    (32 KB)
    //   cand_v[N*12] f32     @ 49152    (1.5 MB)
    //   cand_i[N*12] u16     @ 1622016  (768 KB)
    //   ebf_p (1 MB panels)  @ 2408448  -> total ~3.46 MB
    int*   counts   = (int*)d_ws;
    float* e2np     = (float*)((char*)d_ws + 8192);
    float* partials = (float*)((char*)d_ws + 16384);
    float* cand_v   = (float*)((char*)d_ws + 49152);
    u16*   cand_i   = (u16*)((char*)d_ws + 1622016);
    char*  ebf_p    = (char*)d_ws + 2408448;

    zero_counts_kernel<<<(K + 255) / 256, 256, 0, stream>>>(counts, K);
    code_norms_np_kernel<<<K, 64, 0, stream>>>(e, e2np);
    convert_permute_e_kernel<<<K * 32 / 256, 256, 0, stream>>>(e, ebf_p);
    vq_cand_kernel<<<dim3(N / 64, NSPLIT), 256, 0, stream>>>(z, ebf_p, e2np, cand_v, cand_i);
    refine_fused_kernel<<<N / 4, 256, 0, stream>>>(z, e, e2np, cand_v, cand_i,
                                                   counts, partials, out_zq, out_idx);
    finalize_kernel<<<1, 256, 0, stream>>>(counts, partials, out_loss, K, N / 4,
                                           1.0f / (float)N, 1.0f / (float)(N * DDIM));
}